// Round 19
// baseline (97.780 us; speedup 1.0000x reference)
//
#include <hip/hip_runtime.h>
#include <math.h>

#define DIM  768
#define NH   12
#define HD   64
#define HWN  1024
#define MROWS 4096
#define LOG2E 1.44269504f

typedef __attribute__((ext_vector_type(8))) short short8;
typedef __attribute__((ext_vector_type(4))) float f32x4;
typedef _Float16 h8 __attribute__((ext_vector_type(8)));
typedef _Float16 h2 __attribute__((ext_vector_type(2)));

__device__ __forceinline__ void gl_lds16(const void* g, void* l) {
    __builtin_amdgcn_global_load_lds(
        (const __attribute__((address_space(1))) void*)g,
        (__attribute__((address_space(3))) void*)l, 16, 0, 0);
}

// raw v_exp_f32: D = 2^S0
__device__ __forceinline__ float fexp2(float x) {
    float r;
    asm("v_exp_f32 %0, %1" : "=v"(r) : "v"(x));
    return r;
}

// ---------------------------------------------------------------------------
// Fused prep: blocks 0..575 wconv | 576 rel2frag | 577.. xconv (grid-stride)
// ---------------------------------------------------------------------------
__global__ __launch_bounds__(256) void prep_kernel(
    const float* __restrict__ q, const float* __restrict__ k,
    const float* __restrict__ v,
    const float* __restrict__ Wq, const float* __restrict__ Wk,
    const float* __restrict__ Wv, const float* __restrict__ Wp,
    const float* __restrict__ rph, const float* __restrict__ rpw,
    _Float16* __restrict__ WtAll, _Float16* __restrict__ relTg,
    _Float16* __restrict__ xf16)
{
    __shared__ float Ws[64][65];
    const int b = blockIdx.x;
    const int t = threadIdx.x;

    if (b < 576) {           // ---- wconv ----
        const int z = b / 144, rem = b - z * 144;
        const int ky = rem / 12, nx = rem - ky * 12;
        const float* W = (z == 0) ? Wq : (z == 1) ? Wk : (z == 2) ? Wv : Wp;
        _Float16* Wt = WtAll + (size_t)z * 589824;
        const int k0 = ky * 64, n0 = nx * 64;
        {
            int r = t >> 2, c4 = (t & 3) * 16;
            #pragma unroll
            for (int u = 0; u < 16; u += 4)
                *(float4*)&Ws[r][c4 + u] = *(const float4*)(W + (size_t)(k0 + r) * DIM + n0 + c4 + u);
        }
        __syncthreads();
        const int n = t >> 2, kseg = (t & 3) * 16;
        h8 h0, h1;
        #pragma unroll
        for (int j = 0; j < 8; ++j) {
            h0[j] = (_Float16)Ws[kseg + j][n];
            h1[j] = (_Float16)Ws[kseg + 8 + j][n];
        }
        size_t base = (size_t)(n0 + n) * DIM + k0 + kseg;
        *(h8*)(Wt + base) = h0;
        *(h8*)(Wt + base + 8) = h1;
    } else if (b == 576) {   // ---- rel2frag ----
        const int row = t >> 1, c0 = (t & 1) * 32;
        const float* src = (row < 63) ? rph + (size_t)row * HD
                         : (row >= 64 && row < 127) ? rpw + (size_t)(row - 64) * HD
                         : nullptr;
        #pragma unroll
        for (int g = 0; g < 4; ++g) {
            h8 o;
            #pragma unroll
            for (int j = 0; j < 8; ++j)
                o[j] = src ? (_Float16)src[c0 + g * 8 + j] : (_Float16)0.0f;
            *(h8*)(relTg + (size_t)row * HD + c0 + g * 8) = o;
        }
    } else {                 // ---- xconv ----
        const int N8 = MROWS * DIM / 8;
        int i = (b - 577) * 256 + t;
        const int stride = (gridDim.x - 577) * 256;
        for (; i < 3 * N8; i += stride) {
            const int sel = i / N8, j = i - sel * N8;
            const float* src = (sel == 0) ? q : (sel == 1) ? k : v;
            float4 a0 = ((const float4*)src)[j * 2];
            float4 a1 = ((const float4*)src)[j * 2 + 1];
            h8 o = {(_Float16)a0.x, (_Float16)a0.y, (_Float16)a0.z, (_Float16)a0.w,
                    (_Float16)a1.x, (_Float16)a1.y, (_Float16)a1.z, (_Float16)a1.w};
            *(h8*)(xf16 + (size_t)sel * (MROWS * DIM) + (size_t)j * 8) = o;
        }
    }
}

// ---------------------------------------------------------------------------
// fp16 MFMA GEMM, MT=64 x 96 tiles, BK=64, rotated single-barrier dbuf:
// stage(kt+1) issued AFTER the barrier -> loads in flight across the whole
// compute phase (no vmcnt(0) drain stall). 40KB LDS -> 4 blocks/CU.
// AMODE 0: q/k/v fused -> 1536 blocks, out fp16 heads.
// AMODE 1: attn-out    -> 512 blocks, out fp32 + bias.
// ---------------------------------------------------------------------------
template<int AMODE>
__global__ __launch_bounds__(256) void gemm_mfma_kernel(
    const _Float16* __restrict__ X0, const _Float16* __restrict__ WtAll,
    const float* __restrict__ bias0, const float* __restrict__ bias1,
    const float* __restrict__ bias2,
    void* __restrict__ Y0, void* __restrict__ Y1, void* __restrict__ Y2)
{
    constexpr int BUFB = 20480;               // 8KB A + 12KB B
    __shared__ __align__(16) char smem[2 * BUFB];

    const int t = threadIdx.x;
    const int w = t >> 6, lane = t & 63;
    const int l15 = lane & 15, l4 = lane >> 4;

    int sel, rb, cb;
    if (AMODE == 0) {
        const int sw = (blockIdx.x & 7) * 192 + (blockIdx.x >> 3);   // 1536
        sel = sw >> 9;
        const int rem = sw & 511;
        rb = rem >> 3; cb = rem & 7;
    } else {
        const int sw = (blockIdx.x & 7) * 64 + (blockIdx.x >> 3);    // 512
        sel = 3;
        rb = sw >> 3; cb = sw & 7;
    }
    const int row0 = rb * 64, col0 = cb * 96;

    const char* Ab = (const char*)(X0 + (AMODE == 0 ? (size_t)sel * (MROWS * DIM) : 0));
    const _Float16* Bt = WtAll + (size_t)sel * 589824;
    const float* bias = (AMODE == 1) ? bias0 : (sel == 0) ? bias0 : (sel == 1) ? bias1 : bias2;

    f32x4 acc[2][3];
    #pragma unroll
    for (int i = 0; i < 2; ++i)
        #pragma unroll
        for (int j = 0; j < 3; ++j) acc[i][j] = (f32x4){0, 0, 0, 0};

    // 8 A-ops (frag rows, swizzled) + 12 B-ops per tile, spread over 4 waves
#define GSTAGE(KT, BUF) {                                                      \
        char* dst = smem + (BUF) * BUFB;                                       \
        _Pragma("unroll")                                                      \
        for (int op = w; op < 20; op += 4) {                                   \
            if (op < 8) {                                                      \
                const int row = op * 8 + (lane >> 3);                          \
                const int srcb = ((lane & 7) * 16) ^ ((row & 7) << 4);         \
                gl_lds16(Ab + (size_t)(row0 + row) * 1536 + (KT) * 128 + srcb, \
                         dst + op * 1024);                                     \
            } else {                                                           \
                const int f = op - 8;                                          \
                const int ks = f / 6, cf = f % 6;                              \
                gl_lds16((const char*)Bt + (size_t)(col0 + cf * 16 + l15) * 1536 \
                         + (KT) * 128 + ks * 64 + l4 * 16,                     \
                         dst + 8192 + f * 1024);                               \
            }                                                                  \
        } }

    GSTAGE(0, 0);

    #pragma unroll 2
    for (int kt = 0; kt < 12; ++kt) {
        __syncthreads();                  // buf[kt&1] ready (prev-iter loads)
        if (kt < 11) GSTAGE(kt + 1, (kt + 1) & 1);
        const char* buf = smem + (kt & 1) * BUFB;

        __builtin_amdgcn_s_setprio(1);
        #pragma unroll
        for (int ks = 0; ks < 2; ++ks) {
            h8 b[3];
            #pragma unroll
            for (int cf4 = 0; cf4 < 3; ++cf4) {
                const int fb = ks * 6 + (w & 1) * 3 + cf4;
                b[cf4] = *(const h8*)(buf + 8192 + fb * 1024 + lane * 16);
            }
            #pragma unroll
            for (int rf = 0; rf < 2; ++rf) {
                const int arow = (w >> 1) * 32 + rf * 16 + l15;
                const int base = arow * 128 + ((ks * 64 + l4 * 16) ^ ((arow & 7) << 4));
                h8 ah = *(const h8*)(buf + base);
                #pragma unroll
                for (int cf4 = 0; cf4 < 3; ++cf4)
                    acc[rf][cf4] = __builtin_amdgcn_mfma_f32_16x16x32_f16(ah, b[cf4], acc[rf][cf4], 0, 0, 0);
            }
        }
        __builtin_amdgcn_s_setprio(0);
    }

    const int wrow0 = row0 + (w >> 1) * 32;
    const int wcol0 = col0 + (w & 1) * 48;
    #pragma unroll
    for (int cf4 = 0; cf4 < 3; ++cf4) {
        const int c = wcol0 + cf4 * 16 + l15;
        const float bb = bias[c];
        #pragma unroll
        for (int rf = 0; rf < 2; ++rf) {
            #pragma unroll
            for (int reg = 0; reg < 4; ++reg) {
                const int r = wrow0 + rf * 16 + l4 * 4 + reg;
                float y = acc[rf][cf4][reg] + bb;
                if (AMODE == 1) {
                    ((float*)Y0)[(size_t)r * DIM + c] = y;
                } else {
                    _Float16* Yh = (_Float16*)((sel == 0) ? Y0 : (sel == 1) ? Y1 : Y2);
                    size_t base = ((size_t)((r >> 10) * NH + (c >> 6)) * HWN + (r & 1023)) * HD + (c & 63);
                    Yh[base] = (_Float16)y;
                }
            }
        }
    }
}

// ---------------------------------------------------------------------------
// fp16 MFMA fused attention — R18 verbatim (measured best, 41.3-42.1 µs).
// ---------------------------------------------------------------------------
#define AT_REL   0        // 8704
#define AT_VT    8704     // 2 x 8192 -> 25088
#define AT_P     25088    // 4 x 2048 -> 33280
#define AT_KB    33280    // 2 x 8192 -> 49664
#define AT_QF    8704     // prologue overlay
#define AT_RELT  17920    // prologue overlay
#define AT_PG    17920    // prologue overlay
#define AT_OF    8704     // epilogue overlay
#define AT_TOTAL 49664

__global__ __launch_bounds__(256, 3) void attn_kernel(
    const _Float16* __restrict__ qh, const _Float16* __restrict__ kh,
    const _Float16* __restrict__ vh, const _Float16* __restrict__ relTg,
    _Float16* __restrict__ aout)
{
    __shared__ __align__(16) char smem[AT_TOTAL];
    const int bid = blockIdx.x;
    const int j   = bid >> 3;
    const int bh  = (bid & 7) * 6 + (j >> 4);
    const int qb  = j & 15;
    const int t  = threadIdx.x;
    const int w  = t >> 6;
    const int lane = t & 63;
    const int l15 = lane & 15, l4 = lane >> 4;

    _Float16* Rel = (_Float16*)(smem + AT_REL);
    _Float16* Qf  = (_Float16*)(smem + AT_QF);

    const int r = t >> 2, dc = (t & 3) * 16;
    {
        const _Float16* qp = qh + ((size_t)bh * HWN + qb * 64 + r) * HD + dc;
        *(short8*)(&Qf[r * 72 + dc])     = *(const short8*)(qp);
        *(short8*)(&Qf[r * 72 + dc + 8]) = *(const short8*)(qp + 8);
        #pragma unroll
        for (int it = 0; it < 4; ++it) {
            const int f = it * 4 + w;
            const int ct = f >> 1, ks = f & 1;
            gl_lds16((const char*)relTg + (ct * 16 + l15) * 128 + ks * 64 + l4 * 16,
                     smem + AT_RELT + f * 1024);
        }
    }
    __syncthreads();

    const _Float16* kb_ = kh + (size_t)bh * HWN * HD;
    const _Float16* vb_ = vh + (size_t)bh * HWN * HD;
    const int key2 = (t & 31) * 2, dgrp = t >> 5;
    short8 rv0, rv1;
#define LOADV(KT) {                                                            \
        const _Float16* vp = vb_ + (size_t)((KT) * 64 + key2) * HD + dgrp * 8; \
        rv0 = *(const short8*)vp; rv1 = *(const short8*)(vp + HD); }
    LOADV(0);

    h8 qf2[2];
    {
        const int qr = w * 16 + l15;
        qf2[0] = *(const h8*)(&Qf[qr * 72 + l4 * 8]);
        qf2[1] = *(const h8*)(&Qf[qr * 72 + 32 + l4 * 8]);
        const _Float16 qs = (_Float16)(0.125f * LOG2E);
        #pragma unroll
        for (int j2 = 0; j2 < 8; ++j2) { qf2[0][j2] *= qs; qf2[1][j2] *= qs; }
    }

    f32x4 pacc[4][2];
    #pragma unroll
    for (int i = 0; i < 4; ++i)
        #pragma unroll
        for (int j2 = 0; j2 < 2; ++j2) pacc[i][j2] = (f32x4){0, 0, 0, 0};
    #pragma unroll
    for (int ks = 0; ks < 2; ++ks) {
        h8 b0 = *(const h8*)(smem + AT_RELT + ((w * 2 + 0) * 2 + ks) * 1024 + lane * 16);
        h8 b1 = *(const h8*)(smem + AT_RELT + ((w * 2 + 1) * 2 + ks) * 1024 + lane * 16);
        #pragma unroll
        for (int rt = 0; rt < 4; ++rt) {
            h8 a = *(const h8*)(&Qf[(rt * 16 + l15) * 72 + ks * 32 + l4 * 8]);
            pacc[rt][0] = __builtin_amdgcn_mfma_f32_16x16x32_f16(a, b0, pacc[rt][0], 0, 0, 0);
            pacc[rt][1] = __builtin_amdgcn_mfma_f32_16x16x32_f16(a, b1, pacc[rt][1], 0, 0, 0);
        }
    }

    __syncthreads();
    _Float16* Pg = (_Float16*)(smem + AT_PG);
    #pragma unroll
    for (int rt = 0; rt < 4; ++rt)
        #pragma unroll
        for (int cb2 = 0; cb2 < 2; ++cb2)
            #pragma unroll
            for (int reg = 0; reg < 4; ++reg)
                Pg[(rt * 16 + l4 * 4 + reg) * 130 + w * 32 + cb2 * 16 + l15] =
                    (_Float16)(pacc[rt][cb2][reg] * LOG2E);
    __syncthreads();

    {
        const int q = t >> 2, kk0 = (t & 3) * 8;
        const int hw = qb * 64 + q;
        const int hq = hw >> 5, wq = hw & 31;
        short8 vh_, vw_;
        #pragma unroll
        for (int j2 = 0; j2 < 8; ++j2) {
            const int kk = kk0 + j2;
            vh_[j2] = *(const short*)&Pg[q * 130 + (hq + 31 - kk)];
            vw_[j2] = *(const short*)&Pg[q * 130 + 64 + (wq + 31 - kk)];
        }
        *(short8*)(&Rel[q * 68 + kk0])      = vh_;
        *(short8*)(&Rel[q * 68 + 32 + kk0]) = vw_;
    }
    __syncthreads();

    const int qrow_bias = w * 16 + l15;
    float rw_[2][4];
    #pragma unroll
    for (int c2 = 0; c2 < 2; ++c2)
        #pragma unroll
        for (int reg = 0; reg < 4; ++reg)
            rw_[c2][reg] = (float)Rel[qrow_bias * 68 + 32 + c2 * 16 + l4 * 4 + reg];

#define STAGEK(KT, BUF) {                                                      \
        _Pragma("unroll")                                                      \
        for (int i2 = 0; i2 < 2; ++i2) {                                       \
            const int f = w * 2 + i2;                                          \
            const int keyk = f * 8 + (lane >> 3);                              \
            const int srcb = ((lane & 7) * 16) ^ ((lane >> 3) << 4);           \
            gl_lds16((const char*)kb_ + (size_t)((KT) * 64 + keyk) * 128 + srcb, \
                     smem + AT_KB + (BUF) * 8192 + f * 1024);                  \
        } }

#define WRITEVT(BUF) {                                                         \
        _Pragma("unroll")                                                      \
        for (int j2 = 0; j2 < 8; ++j2) {                                       \
            const int d = dgrp * 8 + j2;                                       \
            unsigned pk = ((unsigned short)rv0[j2]) |                          \
                          (((unsigned)(unsigned short)rv1[j2]) << 16);         \
            *(unsigned*)(smem + AT_VT + (BUF) * 8192 + d * 128 +               \
                         ((key2 * 2) ^ ((d & 7) << 4))) = pk; } }
    WRITEVT(0);
    STAGEK(0, 0);

    f32x4 acc_o[4] = {{0,0,0,0},{0,0,0,0},{0,0,0,0},{0,0,0,0}};
    float m_ = -INFINITY, lsum = 0.f;
    char* Pw = smem + AT_P + w * 2048;
    const int swzP = (l15 & 7) << 4;

    #pragma unroll 2
    for (int kt = 0; kt < 16; ++kt) {
        const int cur = kt & 1;
        __syncthreads();
        if (kt < 15) { LOADV(kt + 1); STAGEK(kt + 1, cur ^ 1); }

        h2 rhp = *(const h2*)(&Rel[qrow_bias * 68 + kt * 2]);
        const float rh0 = (float)rhp[0];
        const float rh1 = (float)rhp[1];
        f32x4 accs[4];
        #pragma unroll
        for (int ct = 0; ct < 4; ++ct) {
            const float rhc = (ct >> 1) ? rh1 : rh0;
            #pragma unroll
            for (int reg = 0; reg < 4; ++reg)
                accs[ct][reg] = rw_[ct & 1][reg] + rhc;
        }
        __builtin_amdgcn_s_setprio(1);
        #pragma unroll
        for (int ct = 0; ct < 4; ++ct) {
            const int row = ct * 16 + l15;
            const int swzK = (row & 7) << 4;
            #pragma unroll
            for (int ks = 0; ks < 2; ++ks) {
                h8 kfr = *(const h8*)(smem + AT_KB + cur * 8192 + row * 128 +
                                      ((ks * 64 + l4 * 16) ^ swzK));
                accs[ct] = __builtin_amdgcn_mfma_f32_16x16x32_f16(kfr, qf2[ks], accs[ct], 0, 0, 0);
            }
        }
        __builtin_amdgcn_s_setprio(0);

        float mx[4];
        #pragma unroll
        for (int ct = 0; ct < 4; ++ct)
            mx[ct] = fmaxf(fmaxf(accs[ct][0], accs[ct][1]),
                           fmaxf(accs[ct][2], accs[ct][3]));
        float tmax = fmaxf(fmaxf(mx[0], mx[1]), fmaxf(mx[2], mx[3]));

        if (__any(tmax > m_ + 11.5416f)) {
            float tg = fmaxf(tmax, __shfl_xor(tmax, 16));
            tg = fmaxf(tg, __shfl_xor(tg, 32));
            const float mnew = fmaxf(m_, tg);
            const float factor = fexp2(m_ - mnew);
            m_ = mnew;
            lsum *= factor;
            #pragma unroll
            for (int reg = 0; reg < 4; ++reg) {
                const float fr = __shfl(factor, l4 * 4 + reg);
                #pragma unroll
                for (int dt = 0; dt < 4; ++dt) acc_o[dt][reg] *= fr;
            }
        }

        float tsum = 0.f;
        #pragma unroll
        for (int ct = 0; ct < 4; ++ct) {
            float p0 = fexp2(accs[ct][0] - m_);
            float p1 = fexp2(accs[ct][1] - m_);
            float p2 = fexp2(accs[ct][2] - m_);
            float p3 = fexp2(accs[ct][3] - m_);
            tsum += (p0 + p1) + (p2 + p3);
            h2 pa = {(_Float16)p0, (_Float16)p1};
            h2 pb = {(_Float16)p2, (_Float16)p3};
            uint2 pk;
            pk.x = *(unsigned*)&pa;
            pk.y = *(unsigned*)&pb;
            *(uint2*)(Pw + l15 * 128 + ((ct * 32 + l4 * 8) ^ swzP)) = pk;
        }
        lsum += tsum;

        __builtin_amdgcn_s_setprio(1);
        #pragma unroll
        for (int ks = 0; ks < 2; ++ks) {
            h8 pa = *(const h8*)(Pw + l15 * 128 + ((ks * 64 + l4 * 16) ^ swzP));
            #pragma unroll
            for (int dt = 0; dt < 4; ++dt) {
                const int d = dt * 16 + l15;
                h8 vf = *(const h8*)(smem + AT_VT + cur * 8192 + d * 128 +
                                     ((ks * 64 + l4 * 16) ^ ((d & 7) << 4)));
                acc_o[dt] = __builtin_amdgcn_mfma_f32_16x16x32_f16(pa, vf, acc_o[dt], 0, 0, 0);
            }
        }
        __builtin_amdgcn_s_setprio(0);

        if (kt < 15) WRITEVT(cur ^ 1);
    }

    float ltot = lsum + __shfl_xor(lsum, 16);
    ltot += __shfl_xor(ltot, 32);
    const float invl = 1.0f / ltot;
    float linv[4];
    #pragma unroll
    for (int reg = 0; reg < 4; ++reg) linv[reg] = __shfl(invl, l4 * 4 + reg);
    __syncthreads();
    _Float16* Of = (_Float16*)(smem + AT_OF);
    #pragma unroll
    for (int reg = 0; reg < 4; ++reg) {
        const int qloc = w * 16 + l4 * 4 + reg;
        #pragma unroll
        for (int dt = 0; dt < 4; ++dt)
            Of[qloc * 72 + dt * 16 + l15] = (_Float16)(acc_o[dt][reg] * linv[reg]);
    }
    __syncthreads();
    {
        const int b_ = bh / NH, nh = bh % NH;
        _Float16* op = aout + ((size_t)b_ * HWN + qb * 64 + r) * DIM + nh * HD + dc;
        *(short8*)op       = *(const short8*)(&Of[r * 72 + dc]);
        *(short8*)(op + 8) = *(const short8*)(&Of[r * 72 + dc + 8]);
    }
}

// ---------------------------------------------------------------------------
extern "C" void kernel_launch(void* const* d_in, const int* in_sizes, int n_in,
                              void* d_out, int out_size, void* d_ws, size_t ws_size,
                              hipStream_t stream) {
    const float* q   = (const float*)d_in[0];
    const float* k   = (const float*)d_in[1];
    const float* v   = (const float*)d_in[2];
    const float* Wq  = (const float*)d_in[3];
    const float* bq  = (const float*)d_in[4];
    const float* Wk  = (const float*)d_in[5];
    const float* bk  = (const float*)d_in[6];
    const float* Wv  = (const float*)d_in[7];
    const float* bv  = (const float*)d_in[8];
    const float* Wp  = (const float*)d_in[9];
    const float* bp  = (const float*)d_in[10];
    const float* rph = (const float*)d_in[11];
    const float* rpw = (const float*)d_in[12];

    float* out = (float*)d_out;
    char*  w0  = (char*)d_ws;

    _Float16* wtAll = (_Float16*)(w0);                // 4,718,592
    _Float16* relTg = (_Float16*)(w0 + 4718592);      //    16,384
    _Float16* xf16  = (_Float16*)(w0 + 4734976);      // 18,874,368
    _Float16* aout  = (_Float16*)(w0 + 4734976);      // overlays xf16
    _Float16* qf16  = (_Float16*)(w0 + 23609344);     // 6,291,456
    _Float16* kf16  = (_Float16*)(w0 + 29900800);     // 6,291,456
    _Float16* vf16  = (_Float16*)(w0 + 36192256);     // 6,291,456

    dim3 blk(256);
    prep_kernel<<<2625, blk, 0, stream>>>(q, k, v, Wq, Wk, Wv, Wp, rph, rpw,
                                          wtAll, relTg, xf16);
    gemm_mfma_kernel<0><<<1536, blk, 0, stream>>>(
        xf16, wtAll, bq, bk, bv, qf16, kf16, vf16);
    attn_kernel<<<768, blk, 0, stream>>>(qf16, kf16, vf16, relTg, aout);
    gemm_mfma_kernel<1><<<512, blk, 0, stream>>>(
        aout, wtAll, bp, nullptr, nullptr, out, nullptr, nullptr);
}

// Round 20
// 90.752 us; speedup vs baseline: 1.0774x; 1.0774x over previous
//
#include <hip/hip_runtime.h>
#include <math.h>

#define DIM  768
#define NH   12
#define HD   64
#define HWN  1024
#define MROWS 4096
#define LOG2E 1.44269504f

typedef __attribute__((ext_vector_type(8))) short short8;
typedef __attribute__((ext_vector_type(4))) float f32x4;
typedef _Float16 h8 __attribute__((ext_vector_type(8)));
typedef _Float16 h2 __attribute__((ext_vector_type(2)));

__device__ __forceinline__ void gl_lds16(const void* g, void* l) {
    __builtin_amdgcn_global_load_lds(
        (const __attribute__((address_space(1))) void*)g,
        (__attribute__((address_space(3))) void*)l, 16, 0, 0);
}

// raw v_exp_f32: D = 2^S0
__device__ __forceinline__ float fexp2(float x) {
    float r;
    asm("v_exp_f32 %0, %1" : "=v"(r) : "v"(x));
    return r;
}

// ---------------------------------------------------------------------------
// Fused prep: blocks 0..575 wconv | 576 rel2frag | 577.. xconv (grid-stride)
// ---------------------------------------------------------------------------
__global__ __launch_bounds__(256) void prep_kernel(
    const float* __restrict__ q, const float* __restrict__ k,
    const float* __restrict__ v,
    const float* __restrict__ Wq, const float* __restrict__ Wk,
    const float* __restrict__ Wv, const float* __restrict__ Wp,
    const float* __restrict__ rph, const float* __restrict__ rpw,
    _Float16* __restrict__ WtAll, _Float16* __restrict__ relTg,
    _Float16* __restrict__ xf16)
{
    __shared__ float Ws[64][65];
    const int b = blockIdx.x;
    const int t = threadIdx.x;

    if (b < 576) {           // ---- wconv ----
        const int z = b / 144, rem = b - z * 144;
        const int ky = rem / 12, nx = rem - ky * 12;
        const float* W = (z == 0) ? Wq : (z == 1) ? Wk : (z == 2) ? Wv : Wp;
        _Float16* Wt = WtAll + (size_t)z * 589824;
        const int k0 = ky * 64, n0 = nx * 64;
        {
            int r = t >> 2, c4 = (t & 3) * 16;
            #pragma unroll
            for (int u = 0; u < 16; u += 4)
                *(float4*)&Ws[r][c4 + u] = *(const float4*)(W + (size_t)(k0 + r) * DIM + n0 + c4 + u);
        }
        __syncthreads();
        const int n = t >> 2, kseg = (t & 3) * 16;
        h8 h0, h1;
        #pragma unroll
        for (int j = 0; j < 8; ++j) {
            h0[j] = (_Float16)Ws[kseg + j][n];
            h1[j] = (_Float16)Ws[kseg + 8 + j][n];
        }
        size_t base = (size_t)(n0 + n) * DIM + k0 + kseg;
        *(h8*)(Wt + base) = h0;
        *(h8*)(Wt + base + 8) = h1;
    } else if (b == 576) {   // ---- rel2frag ----
        const int row = t >> 1, c0 = (t & 1) * 32;
        const float* src = (row < 63) ? rph + (size_t)row * HD
                         : (row >= 64 && row < 127) ? rpw + (size_t)(row - 64) * HD
                         : nullptr;
        #pragma unroll
        for (int g = 0; g < 4; ++g) {
            h8 o;
            #pragma unroll
            for (int j = 0; j < 8; ++j)
                o[j] = src ? (_Float16)src[c0 + g * 8 + j] : (_Float16)0.0f;
            *(h8*)(relTg + (size_t)row * HD + c0 + g * 8) = o;
        }
    } else {                 // ---- xconv ----
        const int N8 = MROWS * DIM / 8;
        int i = (b - 577) * 256 + t;
        const int stride = (gridDim.x - 577) * 256;
        for (; i < 3 * N8; i += stride) {
            const int sel = i / N8, j = i - sel * N8;
            const float* src = (sel == 0) ? q : (sel == 1) ? k : v;
            float4 a0 = ((const float4*)src)[j * 2];
            float4 a1 = ((const float4*)src)[j * 2 + 1];
            h8 o = {(_Float16)a0.x, (_Float16)a0.y, (_Float16)a0.z, (_Float16)a0.w,
                    (_Float16)a1.x, (_Float16)a1.y, (_Float16)a1.z, (_Float16)a1.w};
            *(h8*)(xf16 + (size_t)sel * (MROWS * DIM) + (size_t)j * 8) = o;
        }
    }
}

// ---------------------------------------------------------------------------
// fp16 MFMA GEMM, 96-wide tiles (R13 verbatim — measured best).
// AMODE 0: tile 128x96, q/k/v fused -> 768 blocks, out fp16 heads.
// AMODE 1: tile  64x96, attn-out    -> 512 blocks, out fp32 + bias.
// ---------------------------------------------------------------------------
template<int AMODE>
__global__ __launch_bounds__(256, 3) void gemm_mfma_kernel(
    const _Float16* __restrict__ X0, const _Float16* __restrict__ WtAll,
    const float* __restrict__ bias0, const float* __restrict__ bias1,
    const float* __restrict__ bias2,
    void* __restrict__ Y0, void* __restrict__ Y1, void* __restrict__ Y2)
{
    constexpr int MT = (AMODE == 0) ? 128 : 64;
    constexpr int RF = MT / 32;
    __shared__ __align__(16) char smem[MT * 128 + 12 * 1024];
    constexpr int BOFF = MT * 128;

    const int t = threadIdx.x;
    const int w = t >> 6, lane = t & 63;
    const int l15 = lane & 15, l4 = lane >> 4;

    int sel, rb, cb;
    if (AMODE == 0) {
        const int sw = (blockIdx.x & 7) * 96 + (blockIdx.x >> 3);
        sel = sw >> 8;
        const int rem = sw & 255;
        rb = rem >> 3; cb = rem & 7;
    } else {
        const int sw = (blockIdx.x & 7) * 64 + (blockIdx.x >> 3);
        sel = 3;
        rb = sw >> 3; cb = sw & 7;
    }
    const int row0 = rb * MT, col0 = cb * 96;

    const char* Ab = (const char*)(X0 + (AMODE == 0 ? (size_t)sel * (MROWS * DIM) : 0));
    const _Float16* Bt = WtAll + (size_t)sel * 589824;
    const float* bias = (AMODE == 1) ? bias0 : (sel == 0) ? bias0 : (sel == 1) ? bias1 : bias2;

    f32x4 acc[RF][3];
    #pragma unroll
    for (int i = 0; i < RF; ++i)
        #pragma unroll
        for (int j = 0; j < 3; ++j) acc[i][j] = (f32x4){0, 0, 0, 0};

    for (int kt = 0; kt < 12; ++kt) {
        #pragma unroll
        for (int i = 0; i < MT / 32; ++i) {
            const int fi = w * (MT / 32) + i;
            const int row = fi * 8 + (lane >> 3);
            const int srcb = ((lane & 7) * 16) ^ ((row & 7) << 4);
            gl_lds16(Ab + (size_t)(row0 + row) * 1536 + kt * 128 + srcb, smem + fi * 1024);
        }
        #pragma unroll
        for (int it = 0; it < 3; ++it) {
            const int f = it * 4 + w;
            const int ks = f / 6, cf = f % 6;
            const size_t off = (size_t)(col0 + cf * 16 + l15) * 1536 + kt * 128 + ks * 64 + l4 * 16;
            gl_lds16((const char*)Bt + off, smem + BOFF + f * 1024);
        }
        __syncthreads();

        __builtin_amdgcn_s_setprio(1);
        #pragma unroll
        for (int ks = 0; ks < 2; ++ks) {
            h8 b[3];
            #pragma unroll
            for (int cf4 = 0; cf4 < 3; ++cf4) {
                const int fb = ks * 6 + (w & 1) * 3 + cf4;
                b[cf4] = *(const h8*)(smem + BOFF + fb * 1024 + lane * 16);
            }
            #pragma unroll
            for (int rf = 0; rf < RF; ++rf) {
                const int arow = (w >> 1) * (MT / 2) + rf * 16 + l15;
                const int base = arow * 128 + ((ks * 64 + l4 * 16) ^ ((arow & 7) << 4));
                h8 ah = *(const h8*)(smem + base);
                #pragma unroll
                for (int cf4 = 0; cf4 < 3; ++cf4)
                    acc[rf][cf4] = __builtin_amdgcn_mfma_f32_16x16x32_f16(ah, b[cf4], acc[rf][cf4], 0, 0, 0);
            }
        }
        __builtin_amdgcn_s_setprio(0);
        __syncthreads();
    }

    const int wrow0 = row0 + (w >> 1) * (MT / 2);
    const int wcol0 = col0 + (w & 1) * 48;
    #pragma unroll
    for (int cf4 = 0; cf4 < 3; ++cf4) {
        const int c = wcol0 + cf4 * 16 + l15;
        const float bb = bias[c];
        #pragma unroll
        for (int rf = 0; rf < RF; ++rf) {
            #pragma unroll
            for (int reg = 0; reg < 4; ++reg) {
                const int r = wrow0 + rf * 16 + l4 * 4 + reg;
                float y = acc[rf][cf4][reg] + bb;
                if (AMODE == 1) {
                    ((float*)Y0)[(size_t)r * DIM + c] = y;
                } else {
                    _Float16* Yh = (_Float16*)((sel == 0) ? Y0 : (sel == 1) ? Y1 : Y2);
                    size_t base = ((size_t)((r >> 10) * NH + (c >> 6)) * HWN + (r & 1023)) * HD + (c & 63);
                    Yh[base] = (_Float16)y;
                }
            }
        }
    }
}

// ---------------------------------------------------------------------------
// fp16 MFMA fused attention — R18 structure (best: 41.3 µs) with direct
// global epilogue store (no LDS staging round-trip, saves 2 barriers).
// ---------------------------------------------------------------------------
#define AT_REL   0        // 8704
#define AT_VT    8704     // 2 x 8192 -> 25088
#define AT_P     25088    // 4 x 2048 -> 33280
#define AT_KB    33280    // 2 x 8192 -> 49664
#define AT_QF    8704     // prologue overlay
#define AT_RELT  17920    // prologue overlay
#define AT_PG    17920    // prologue overlay
#define AT_TOTAL 49664

__global__ __launch_bounds__(256, 3) void attn_kernel(
    const _Float16* __restrict__ qh, const _Float16* __restrict__ kh,
    const _Float16* __restrict__ vh, const _Float16* __restrict__ relTg,
    _Float16* __restrict__ aout)
{
    __shared__ __align__(16) char smem[AT_TOTAL];
    const int bid = blockIdx.x;
    const int j   = bid >> 3;
    const int bh  = (bid & 7) * 6 + (j >> 4);   // 0..47 (XCD owns 6 heads)
    const int qb  = j & 15;                     // 0..15
    const int t  = threadIdx.x;
    const int w  = t >> 6;
    const int lane = t & 63;
    const int l15 = lane & 15, l4 = lane >> 4;

    _Float16* Rel = (_Float16*)(smem + AT_REL);
    _Float16* Qf  = (_Float16*)(smem + AT_QF);

    const int r = t >> 2, dc = (t & 3) * 16;
    {
        const _Float16* qp = qh + ((size_t)bh * HWN + qb * 64 + r) * HD + dc;
        *(short8*)(&Qf[r * 72 + dc])     = *(const short8*)(qp);
        *(short8*)(&Qf[r * 72 + dc + 8]) = *(const short8*)(qp + 8);
        #pragma unroll
        for (int it = 0; it < 4; ++it) {
            const int f = it * 4 + w;
            const int ct = f >> 1, ks = f & 1;
            gl_lds16((const char*)relTg + (ct * 16 + l15) * 128 + ks * 64 + l4 * 16,
                     smem + AT_RELT + f * 1024);
        }
    }
    __syncthreads();

    const _Float16* kb_ = kh + (size_t)bh * HWN * HD;
    const _Float16* vb_ = vh + (size_t)bh * HWN * HD;
    const int key2 = (t & 31) * 2, dgrp = t >> 5;
    short8 rv0, rv1;
#define LOADV(KT) {                                                            \
        const _Float16* vp = vb_ + (size_t)((KT) * 64 + key2) * HD + dgrp * 8; \
        rv0 = *(const short8*)vp; rv1 = *(const short8*)(vp + HD); }
    LOADV(0);

    // Q fragments (B-operand), pre-scaled by (1/8)*log2e  [exp2 domain]
    h8 qf2[2];
    {
        const int qr = w * 16 + l15;
        qf2[0] = *(const h8*)(&Qf[qr * 72 + l4 * 8]);
        qf2[1] = *(const h8*)(&Qf[qr * 72 + 32 + l4 * 8]);
        const _Float16 qs = (_Float16)(0.125f * LOG2E);
        #pragma unroll
        for (int j2 = 0; j2 < 8; ++j2) { qf2[0][j2] *= qs; qf2[1][j2] *= qs; }
    }

    f32x4 pacc[4][2];
    #pragma unroll
    for (int i = 0; i < 4; ++i)
        #pragma unroll
        for (int j2 = 0; j2 < 2; ++j2) pacc[i][j2] = (f32x4){0, 0, 0, 0};
    #pragma unroll
    for (int ks = 0; ks < 2; ++ks) {
        h8 b0 = *(const h8*)(smem + AT_RELT + ((w * 2 + 0) * 2 + ks) * 1024 + lane * 16);
        h8 b1 = *(const h8*)(smem + AT_RELT + ((w * 2 + 1) * 2 + ks) * 1024 + lane * 16);
        #pragma unroll
        for (int rt = 0; rt < 4; ++rt) {
            h8 a = *(const h8*)(&Qf[(rt * 16 + l15) * 72 + ks * 32 + l4 * 8]);
            pacc[rt][0] = __builtin_amdgcn_mfma_f32_16x16x32_f16(a, b0, pacc[rt][0], 0, 0, 0);
            pacc[rt][1] = __builtin_amdgcn_mfma_f32_16x16x32_f16(a, b1, pacc[rt][1], 0, 0, 0);
        }
    }

    __syncthreads();
    // Pg stores bias * log2e (exp2 domain)
    _Float16* Pg = (_Float16*)(smem + AT_PG);
    #pragma unroll
    for (int rt = 0; rt < 4; ++rt)
        #pragma unroll
        for (int cb2 = 0; cb2 < 2; ++cb2)
            #pragma unroll
            for (int reg = 0; reg < 4; ++reg)
                Pg[(rt * 16 + l4 * 4 + reg) * 130 + w * 32 + cb2 * 16 + l15] =
                    (_Float16)(pacc[rt][cb2][reg] * LOG2E);
    __syncthreads();

    {
        const int q = t >> 2, kk0 = (t & 3) * 8;
        const int hw = qb * 64 + q;
        const int hq = hw >> 5, wq = hw & 31;
        short8 vh_, vw_;
        #pragma unroll
        for (int j2 = 0; j2 < 8; ++j2) {
            const int kk = kk0 + j2;
            vh_[j2] = *(const short*)&Pg[q * 130 + (hq + 31 - kk)];
            vw_[j2] = *(const short*)&Pg[q * 130 + 64 + (wq + 31 - kk)];
        }
        *(short8*)(&Rel[q * 68 + kk0])      = vh_;
        *(short8*)(&Rel[q * 68 + 32 + kk0]) = vw_;
    }
    __syncthreads();

    const int qrow_bias = w * 16 + l15;
    float rw_[2][4];
    #pragma unroll
    for (int c2 = 0; c2 < 2; ++c2)
        #pragma unroll
        for (int reg = 0; reg < 4; ++reg)
            rw_[c2][reg] = (float)Rel[qrow_bias * 68 + 32 + c2 * 16 + l4 * 4 + reg];

#define STAGEK(KT, BUF) {                                                      \
        _Pragma("unroll")                                                      \
        for (int i2 = 0; i2 < 2; ++i2) {                                       \
            const int f = w * 2 + i2;                                          \
            const int keyk = f * 8 + (lane >> 3);                              \
            const int srcb = ((lane & 7) * 16) ^ ((lane >> 3) << 4);           \
            gl_lds16((const char*)kb_ + (size_t)((KT) * 64 + keyk) * 128 + srcb, \
                     smem + AT_KB + (BUF) * 8192 + f * 1024);                  \
        } }

#define WRITEVT(BUF) {                                                         \
        _Pragma("unroll")                                                      \
        for (int j2 = 0; j2 < 8; ++j2) {                                       \
            const int d = dgrp * 8 + j2;                                       \
            unsigned pk = ((unsigned short)rv0[j2]) |                          \
                          (((unsigned)(unsigned short)rv1[j2]) << 16);         \
            *(unsigned*)(smem + AT_VT + (BUF) * 8192 + d * 128 +               \
                         ((key2 * 2) ^ ((d & 7) << 4))) = pk; } }
    WRITEVT(0);
    STAGEK(0, 0);

    f32x4 acc_o[4] = {{0,0,0,0},{0,0,0,0},{0,0,0,0},{0,0,0,0}};
    float m_ = -INFINITY, lsum = 0.f;
    char* Pw = smem + AT_P + w * 2048;
    const int swzP = (l15 & 7) << 4;

    #pragma unroll 2
    for (int kt = 0; kt < 16; ++kt) {
        const int cur = kt & 1;
        __syncthreads();
        if (kt < 15) { LOADV(kt + 1); STAGEK(kt + 1, cur ^ 1); }

        h2 rhp = *(const h2*)(&Rel[qrow_bias * 68 + kt * 2]);
        const float rh0 = (float)rhp[0];
        const float rh1 = (float)rhp[1];
        f32x4 accs[4];
        #pragma unroll
        for (int ct = 0; ct < 4; ++ct) {
            const float rhc = (ct >> 1) ? rh1 : rh0;
            #pragma unroll
            for (int reg = 0; reg < 4; ++reg)
                accs[ct][reg] = rw_[ct & 1][reg] + rhc;
        }
        __builtin_amdgcn_s_setprio(1);
        #pragma unroll
        for (int ct = 0; ct < 4; ++ct) {
            const int row = ct * 16 + l15;
            const int swzK = (row & 7) << 4;
            #pragma unroll
            for (int ks = 0; ks < 2; ++ks) {
                h8 kfr = *(const h8*)(smem + AT_KB + cur * 8192 + row * 128 +
                                      ((ks * 64 + l4 * 16) ^ swzK));
                accs[ct] = __builtin_amdgcn_mfma_f32_16x16x32_f16(kfr, qf2[ks], accs[ct], 0, 0, 0);
            }
        }
        __builtin_amdgcn_s_setprio(0);

        float mx[4];
        #pragma unroll
        for (int ct = 0; ct < 4; ++ct)
            mx[ct] = fmaxf(fmaxf(accs[ct][0], accs[ct][1]),
                           fmaxf(accs[ct][2], accs[ct][3]));
        float tmax = fmaxf(fmaxf(mx[0], mx[1]), fmaxf(mx[2], mx[3]));

        if (__any(tmax > m_ + 11.5416f)) {
            float tg = fmaxf(tmax, __shfl_xor(tmax, 16));
            tg = fmaxf(tg, __shfl_xor(tg, 32));
            const float mnew = fmaxf(m_, tg);
            const float factor = fexp2(m_ - mnew);
            m_ = mnew;
            lsum *= factor;
            #pragma unroll
            for (int reg = 0; reg < 4; ++reg) {
                const float fr = __shfl(factor, l4 * 4 + reg);
                #pragma unroll
                for (int dt = 0; dt < 4; ++dt) acc_o[dt][reg] *= fr;
            }
        }

        float tsum = 0.f;
        #pragma unroll
        for (int ct = 0; ct < 4; ++ct) {
            float p0 = fexp2(accs[ct][0] - m_);
            float p1 = fexp2(accs[ct][1] - m_);
            float p2 = fexp2(accs[ct][2] - m_);
            float p3 = fexp2(accs[ct][3] - m_);
            tsum += (p0 + p1) + (p2 + p3);
            h2 pa = {(_Float16)p0, (_Float16)p1};
            h2 pb = {(_Float16)p2, (_Float16)p3};
            uint2 pk;
            pk.x = *(unsigned*)&pa;
            pk.y = *(unsigned*)&pb;
            *(uint2*)(Pw + l15 * 128 + ((ct * 32 + l4 * 8) ^ swzP)) = pk;
        }
        lsum += tsum;

        __builtin_amdgcn_s_setprio(1);
        #pragma unroll
        for (int ks = 0; ks < 2; ++ks) {
            h8 pa = *(const h8*)(Pw + l15 * 128 + ((ks * 64 + l4 * 16) ^ swzP));
            #pragma unroll
            for (int dt = 0; dt < 4; ++dt) {
                const int d = dt * 16 + l15;
                h8 vf = *(const h8*)(smem + AT_VT + cur * 8192 + d * 128 +
                                     ((ks * 64 + l4 * 16) ^ ((d & 7) << 4)));
                acc_o[dt] = __builtin_amdgcn_mfma_f32_16x16x32_f16(pa, vf, acc_o[dt], 0, 0, 0);
            }
        }
        __builtin_amdgcn_s_setprio(0);

        if (kt < 15) WRITEVT(cur ^ 1);
    }

    // ---- final l reduction + DIRECT global epilogue (no LDS staging) ----
    float ltot = lsum + __shfl_xor(lsum, 16);
    ltot += __shfl_xor(ltot, 32);
    const float invl = 1.0f / ltot;
    float linv[4];
    #pragma unroll
    for (int reg = 0; reg < 4; ++reg) linv[reg] = __shfl(invl, l4 * 4 + reg);
    {
        const int b_ = bh / NH, nh = bh % NH;
        #pragma unroll
        for (int reg = 0; reg < 4; ++reg) {
            const int qloc = w * 16 + l4 * 4 + reg;
            _Float16* op = aout + ((size_t)b_ * HWN + qb * 64 + qloc) * DIM + nh * HD + l15;
            #pragma unroll
            for (int dt = 0; dt < 4; ++dt)
                op[dt * 16] = (_Float16)(acc_o[dt][reg] * linv[reg]);
        }
    }
}

// ---------------------------------------------------------------------------
extern "C" void kernel_launch(void* const* d_in, const int* in_sizes, int n_in,
                              void* d_out, int out_size, void* d_ws, size_t ws_size,
                              hipStream_t stream) {
    const float* q   = (const float*)d_in[0];
    const float* k   = (const float*)d_in[1];
    const float* v   = (const float*)d_in[2];
    const float* Wq  = (const float*)d_in[3];
    const float* bq  = (const float*)d_in[4];
    const float* Wk  = (const float*)d_in[5];
    const float* bk  = (const float*)d_in[6];
    const float* Wv  = (const float*)d_in[7];
    const float* bv  = (const float*)d_in[8];
    const float* Wp  = (const float*)d_in[9];
    const float* bp  = (const float*)d_in[10];
    const float* rph = (const float*)d_in[11];
    const float* rpw = (const float*)d_in[12];

    float* out = (float*)d_out;
    char*  w0  = (char*)d_ws;

    _Float16* wtAll = (_Float16*)(w0);                // 4,718,592
    _Float16* relTg = (_Float16*)(w0 + 4718592);      //    16,384
    _Float16* xf16  = (_Float16*)(w0 + 4734976);      // 18,874,368
    _Float16* aout  = (_Float16*)(w0 + 4734976);      // overlays xf16
    _Float16* qf16  = (_Float16*)(w0 + 23609344);     // 6,291,456
    _Float16* kf16  = (_Float16*)(w0 + 29900800);     // 6,291,456
    _Float16* vf16  = (_Float16*)(w0 + 36192256);     // 6,291,456

    dim3 blk(256);
    prep_kernel<<<2625, blk, 0, stream>>>(q, k, v, Wq, Wk, Wv, Wp, rph, rpw,
                                          wtAll, relTg, xf16);
    gemm_mfma_kernel<0><<<768, blk, 0, stream>>>(
        xf16, wtAll, bq, bk, bv, qf16, kf16, vf16);
    attn_kernel<<<768, blk, 0, stream>>>(qf16, kf16, vf16, relTg, aout);
    gemm_mfma_kernel<1><<<512, blk, 0, stream>>>(
        aout, wtAll, bp, nullptr, nullptr, out, nullptr, nullptr);
}